// Round 2
// baseline (1391.875 us; speedup 1.0000x reference)
//
#include <hip/hip_runtime.h>

// ---- problem constants ----
#define BATCH 16
#define RB    8
#define CITIES 1023
#define NODES 1024
#define HDIM  64
#define H2DIM 128
#define KTOT  4096          // 4 poly terms * 1024 (c padded to 1024)
#define KCH   1024          // split-K chunk (x4)
#define KSTEPS 32           // 1024/32

// sigmoid(x) ~= 0.5 + C1*x + C3*x^3 + C5*x^5 on [-1,1], max err ~4e-6
#define C1f 0.24998145f
#define C3f (-0.02068089f)
#define C5f 0.00176243f

typedef __bf16 bf16x8 __attribute__((ext_vector_type(8)));
typedef float  f32x4  __attribute__((ext_vector_type(4)));

__device__ __forceinline__ f32x4 mfma16(bf16x8 a, bf16x8 b, f32x4 c){
    return __builtin_amdgcn_mfma_f32_16x16x32_bf16(a, b, c, 0, 0, 0);
}
__device__ __forceinline__ unsigned short f2b(float f){
    __bf16 b = (__bf16)f;
    return __builtin_bit_cast(unsigned short, b);
}
__device__ __forceinline__ float b2f(unsigned short u){
    unsigned int t = ((unsigned int)u) << 16;
    return __builtin_bit_cast(float, t);
}
__device__ __forceinline__ unsigned short f2h(float f){
    _Float16 h = (_Float16)f;
    return __builtin_bit_cast(unsigned short, h);
}
__device__ __forceinline__ float h2f(unsigned short u){
    return (float)__builtin_bit_cast(_Float16, u);
}

// ---------------- kernel: x_a[b,n] = max_r x_a_state*(assign_prev+action) ----------------
__global__ __launch_bounds__(256) void xa_k(const float* __restrict__ xs,
        const float* __restrict__ ap, const float* __restrict__ act,
        float* __restrict__ xa){
    int idx = blockIdx.x*256 + threadIdx.x;       // 16384
    int b = idx >> 10, n = idx & 1023;
    float m = -1e30f;
    #pragma unroll
    for(int r=0;r<RB;r++){
        size_t o = (((size_t)b*RB + r)<<10) + n;
        m = fmaxf(m, xs[o]*(ap[o]+act[o]));
    }
    xa[idx] = m;
}

// ---------------- presence MLP + softmax over n; writes p,d (fp16, [b][c][n]) ------------
__global__ __launch_bounds__(256) void presence_k(const float* __restrict__ edge,
        const float* __restrict__ W1, const float* __restrict__ W2,
        const float* __restrict__ avail,
        unsigned short* __restrict__ P, unsigned short* __restrict__ D){
    int c = blockIdx.x, b = blockIdx.y;
    int tid = threadIdx.x;
    __shared__ float4 Wl[64];
    __shared__ float red[4];
    if(tid < 64) Wl[tid] = make_float4(W1[tid], W1[64+tid], W1[128+tid], W2[tid]);
    __syncthreads();
    float lg[4], d0[4], ex[4];
    size_t ebase = (((size_t)b*CITIES + c)<<10)*3;
    for(int j=0;j<4;j++){
        int n = tid + j*256;
        size_t ea = ebase + (size_t)n*3;
        float e0 = edge[ea], e1 = edge[ea+1], e2 = edge[ea+2];
        d0[j] = e0;
        float v = 0.f;
        #pragma unroll
        for(int h=0;h<64;h++){
            float4 w = Wl[h];
            float a = fmaf(e0,w.x, fmaf(e1,w.y, e2*w.z));
            v = fmaf(fmaxf(a,0.f), w.w, v);
        }
        float h2 = fmaxf(v, 0.f);                  // relu; /TAU with TAU=1
        float mk = (n==c) ? 0.f : avail[(b<<10)+n];
        lg[j] = h2*mk - (1.f-mk)*1e10f;
    }
    int wv = tid>>6, ln = tid&63;
    float mx = fmaxf(fmaxf(lg[0],lg[1]), fmaxf(lg[2],lg[3]));
    for(int o=32;o>0;o>>=1) mx = fmaxf(mx, __shfl_xor(mx,o,64));
    if(ln==0) red[wv]=mx;
    __syncthreads();
    mx = fmaxf(fmaxf(red[0],red[1]), fmaxf(red[2],red[3]));
    __syncthreads();
    float s = 0.f;
    for(int j=0;j<4;j++){ ex[j] = expf(lg[j]-mx); s += ex[j]; }
    for(int o=32;o>0;o>>=1) s += __shfl_xor(s,o,64);
    if(ln==0) red[wv]=s;
    __syncthreads();
    s = red[0]+red[1]+red[2]+red[3];
    float inv = 1.f/s;
    size_t pbase = ((size_t)b*CITIES + c)<<10;
    for(int j=0;j<4;j++){
        int n = tid + j*256;
        P[pbase+n] = f2h(ex[j]*inv);
        D[pbase+n] = f2h(d0[j]);
    }
}

// ------- build A' [b][i][4*1024] bf16 = {p, p*d, p*d^3, p*d^5} transposed ----------------
__global__ __launch_bounds__(256) void abuild_k(const unsigned short* __restrict__ P,
        const unsigned short* __restrict__ D, unsigned short* __restrict__ A){
    int ct = blockIdx.x, nt = blockIdx.y, b = blockIdx.z;
    int tid = threadIdx.x;
    __shared__ unsigned short Pt[32][36];
    __shared__ unsigned short Dt[32][36];
    {
        int crow = tid>>3, ng = (tid&7)<<2;
        int c = ct*32 + crow;
        if(c < CITIES){
            size_t o = (((size_t)b*CITIES + c)<<10) + nt*32 + ng;
            *(ushort4*)&Pt[crow][ng] = *(const ushort4*)&P[o];
            *(ushort4*)&Dt[crow][ng] = *(const ushort4*)&D[o];
        } else {
            ushort4 z; z.x=0;z.y=0;z.z=0;z.w=0;
            *(ushort4*)&Pt[crow][ng] = z;
            *(ushort4*)&Dt[crow][ng] = z;
        }
    }
    __syncthreads();
    int nrow = tid>>3, cg = (tid&7)<<2;
    ushort4 w0, w1, w2, w3;
    #pragma unroll
    for(int j=0;j<4;j++){
        float p = h2f(Pt[cg+j][nrow]);
        float d = h2f(Dt[cg+j][nrow]);
        float d2 = d*d, d3 = d2*d, d5 = d3*d2;
        ((unsigned short*)&w0)[j] = f2b(p);
        ((unsigned short*)&w1)[j] = f2b(p*d);
        ((unsigned short*)&w2)[j] = f2b(p*d3);
        ((unsigned short*)&w3)[j] = f2b(p*d5);
    }
    size_t abase = ((size_t)(b<<10) + nt*32 + nrow)*KTOT + ct*32 + cg;
    *(ushort4*)&A[abase]      = w0;
    *(ushort4*)&A[abase+1024] = w1;
    *(ushort4*)&A[abase+2048] = w2;
    *(ushort4*)&A[abase+3072] = w3;
}

// ---------------- initial B'^T [b][h][kc] = q_k(h) * U0[b][c][h] -------------------------
__global__ __launch_bounds__(256) void binit_k(const float* __restrict__ U0,
        const float* __restrict__ We, unsigned short* __restrict__ BT, int nout){
    int kc = blockIdx.x*256 + threadIdx.x;   // 0..4095
    int h = blockIdx.y, b = blockIdx.z;
    int k = kc >> 10, c = kc & 1023;
    float we = We[h];
    float we2 = we*we;
    float q = (k==0) ? 0.5f : (k==1 ? C1f*we : (k==2 ? C3f*we*we2 : C5f*we*we2*we2));
    float u = (c < CITIES) ? U0[(((size_t)b<<10) + c)*nout + h] : 0.f;
    BT[((size_t)(b*nout + h))*KTOT + kc] = f2b(q*u);
}

// ---------------- main GEMM: partial[ks][b][i][h] = A'[i, ks-chunk] @ B'[ks-chunk, h] ----
template<int NOUT>
__global__ __launch_bounds__(256) void gemm_k(const unsigned short* __restrict__ Ap,
        const unsigned short* __restrict__ BT, float* __restrict__ partial){
    int mt = blockIdx.x, b = blockIdx.y, ks = blockIdx.z;
    int tid = threadIdx.x;
    int wave = tid>>6, lane = tid&63, quad = lane>>4, l16 = lane&15;
    __shared__ __align__(16) unsigned short At[128*32];
    __shared__ __align__(16) unsigned short Bt[NOUT*32];
    f32x4 zero = {0.f,0.f,0.f,0.f};
    f32x4 acc[2][NOUT/16];
    #pragma unroll
    for(int s=0;s<2;s++)
        #pragma unroll
        for(int nt=0;nt<NOUT/16;nt++) acc[s][nt] = zero;

    const size_t Abase = ((size_t)(b<<10) + mt*128)*KTOT;
    const size_t Bbase = (size_t)b*NOUT*KTOT;
    int r = tid>>2, cg = (tid&3)<<3;
    int k0 = ks*KCH;
    for(int kk=0;kk<KSTEPS;kk++,k0+=32){
        __syncthreads();
        *(uint4*)&At[r*32+cg]        = *(const uint4*)&Ap[Abase + (size_t)r*KTOT      + k0 + cg];
        *(uint4*)&At[(r+64)*32+cg]   = *(const uint4*)&Ap[Abase + (size_t)(r+64)*KTOT + k0 + cg];
        #pragma unroll
        for(int h = r; h < NOUT; h += 64)
            *(uint4*)&Bt[h*32+cg]    = *(const uint4*)&BT[Bbase + (size_t)h*KTOT + k0 + cg];
        __syncthreads();
        bf16x8 a0 = *(const bf16x8*)&At[(wave*32      + l16)*32 + quad*8];
        bf16x8 a1 = *(const bf16x8*)&At[(wave*32 + 16 + l16)*32 + quad*8];
        #pragma unroll
        for(int nt=0; nt<NOUT/16; nt++){
            bf16x8 bf = *(const bf16x8*)&Bt[(nt*16 + l16)*32 + quad*8];
            acc[0][nt] = mfma16(a0, bf, acc[0][nt]);
            acc[1][nt] = mfma16(a1, bf, acc[1][nt]);
        }
    }
    float* pp = partial + (((size_t)(ks*BATCH + b)<<10) + mt*128)*NOUT;
    #pragma unroll
    for(int s=0;s<2;s++)
        #pragma unroll
        for(int nt=0;nt<NOUT/16;nt++){
            int row = wave*32 + s*16 + quad*4;
            int col = nt*16 + l16;
            #pragma unroll
            for(int rr=0;rr<4;rr++)
                pp[(size_t)(row+rr)*NOUT + col] = acc[s][nt][rr];
        }
}

// ---- T1 reduce + epilogue: u = relu(l@W_l + x_a*W_x); emit next B'. hi/lo 3-product ----
#define SR 72
template<bool LAST>
__global__ __launch_bounds__(256) void reduce1_k(const float* __restrict__ partial,
        const float* __restrict__ Wl1a, const float* __restrict__ Wl1b,
        const float* __restrict__ Wx1a, const float* __restrict__ Wx1b,
        const float* __restrict__ We1a, const float* __restrict__ xa,
        unsigned short* __restrict__ Bnext, float* __restrict__ ua, float* __restrict__ ub){
    int mt = blockIdx.x, b = blockIdx.y;
    int i0 = mt*64;
    int tid = threadIdx.x, wave=tid>>6, lane=tid&63, quad=lane>>4, l16=lane&15;
    __shared__ __align__(16) unsigned short Lh[64*SR], Ll[64*SR];
    __shared__ __align__(16) unsigned short Wh[64*SR], Wo[64*SR];
    {
        int k = tid>>2, n0 = (tid&3)*16;
        for(int j=0;j<16;j++){
            float w = Wl1a[k*64 + n0 + j];
            unsigned short hh = f2b(w);
            Wh[(n0+j)*SR + k] = hh;
            Wo[(n0+j)*SR + k] = f2b(w - b2f(hh));
        }
        int i = tid>>2, h0 = (tid&3)*16;
        const float* pp = partial + (((size_t)b<<10)+i0+i)*64 + h0;
        const size_t kss = (size_t)BATCH*1024*64;
        #pragma unroll
        for(int j=0;j<4;j++){
            float4 v0 = *(const float4*)(pp + j*4);
            float4 v1 = *(const float4*)(pp + kss + j*4);
            float4 v2 = *(const float4*)(pp + 2*kss + j*4);
            float4 v3 = *(const float4*)(pp + 3*kss + j*4);
            float vv[4] = {v0.x+v1.x+v2.x+v3.x, v0.y+v1.y+v2.y+v3.y,
                           v0.z+v1.z+v2.z+v3.z, v0.w+v1.w+v2.w+v3.w};
            #pragma unroll
            for(int t=0;t<4;t++){
                unsigned short hh = f2b(vv[t]);
                Lh[i*SR + h0 + j*4 + t] = hh;
                Ll[i*SR + h0 + j*4 + t] = f2b(vv[t] - b2f(hh));
            }
        }
    }
    __syncthreads();
    f32x4 zero = {0.f,0.f,0.f,0.f};
    f32x4 acc[4] = {zero,zero,zero,zero};
    #pragma unroll
    for(int kc=0;kc<2;kc++){
        bf16x8 ah = *(const bf16x8*)&Lh[(wave*16+l16)*SR + kc*32 + quad*8];
        bf16x8 al = *(const bf16x8*)&Ll[(wave*16+l16)*SR + kc*32 + quad*8];
        #pragma unroll
        for(int nt=0;nt<4;nt++){
            bf16x8 bh = *(const bf16x8*)&Wh[(nt*16+l16)*SR + kc*32 + quad*8];
            bf16x8 bl = *(const bf16x8*)&Wo[(nt*16+l16)*SR + kc*32 + quad*8];
            acc[nt] = mfma16(ah, bh, acc[nt]);
            acc[nt] = mfma16(ah, bl, acc[nt]);
            acc[nt] = mfma16(al, bh, acc[nt]);
        }
    }
    int gi = i0 + wave*16 + quad*4;
    float4 xav = *(const float4*)&xa[(b<<10) + gi];
    float xr[4] = {xav.x, xav.y, xav.z, xav.w};
    if(!LAST){
        #pragma unroll
        for(int nt=0;nt<4;nt++){
            int h = nt*16 + l16;
            float wx = Wx1a[h];
            float we = We1a[h];
            float we2 = we*we;
            float q1 = C1f*we, q2 = C3f*we*we2, q3 = C5f*we*we2*we2;
            ushort4 w0,w1,w2,w3;
            #pragma unroll
            for(int rr=0;rr<4;rr++){
                float u = fmaxf(acc[nt][rr] + xr[rr]*wx, 0.f);
                bool pad = (gi+rr == 1023);
                ((unsigned short*)&w0)[rr] = pad?(unsigned short)0:f2b(0.5f*u);
                ((unsigned short*)&w1)[rr] = pad?(unsigned short)0:f2b(q1*u);
                ((unsigned short*)&w2)[rr] = pad?(unsigned short)0:f2b(q2*u);
                ((unsigned short*)&w3)[rr] = pad?(unsigned short)0:f2b(q3*u);
            }
            size_t base = ((size_t)(b*64 + h))*KTOT + gi;
            *(ushort4*)&Bnext[base]      = w0;
            *(ushort4*)&Bnext[base+1024] = w1;
            *(ushort4*)&Bnext[base+2048] = w2;
            *(ushort4*)&Bnext[base+3072] = w3;
        }
    } else {
        #pragma unroll
        for(int nt=0;nt<4;nt++){
            int h = nt*16+l16; float wx = Wx1a[h];
            #pragma unroll
            for(int rr=0;rr<4;rr++)
                ua[(((size_t)b<<10)+gi+rr)*64 + h] = fmaxf(acc[nt][rr] + xr[rr]*wx, 0.f);
        }
        __syncthreads();
        { int k = tid>>2, n0 = (tid&3)*16;
          for(int j=0;j<16;j++){
              float w = Wl1b[k*64 + n0 + j];
              unsigned short hh = f2b(w);
              Wh[(n0+j)*SR + k] = hh;
              Wo[(n0+j)*SR + k] = f2b(w - b2f(hh));
          } }
        __syncthreads();
        f32x4 acc2[4] = {zero,zero,zero,zero};
        #pragma unroll
        for(int kc=0;kc<2;kc++){
            bf16x8 ah = *(const bf16x8*)&Lh[(wave*16+l16)*SR + kc*32 + quad*8];
            bf16x8 al = *(const bf16x8*)&Ll[(wave*16+l16)*SR + kc*32 + quad*8];
            #pragma unroll
            for(int nt=0;nt<4;nt++){
                bf16x8 bh = *(const bf16x8*)&Wh[(nt*16+l16)*SR + kc*32 + quad*8];
                bf16x8 bl = *(const bf16x8*)&Wo[(nt*16+l16)*SR + kc*32 + quad*8];
                acc2[nt] = mfma16(ah, bh, acc2[nt]);
                acc2[nt] = mfma16(ah, bl, acc2[nt]);
                acc2[nt] = mfma16(al, bh, acc2[nt]);
            }
        }
        #pragma unroll
        for(int nt=0;nt<4;nt++){
            int h = nt*16+l16; float wx = Wx1b[h];
            #pragma unroll
            for(int rr=0;rr<4;rr++)
                ub[(((size_t)b<<10)+gi+rr)*64 + h] = fmaxf(acc2[nt][rr] + xr[rr]*wx, 0.f);
        }
    }
}

// ---------------- x2 = concat(ua,ub) @ W_x_2  (hi/lo MFMA, 2 K-phases) -------------------
__global__ __launch_bounds__(256) void x2_k(const float* __restrict__ ua,
        const float* __restrict__ ub, const float* __restrict__ Wx2,
        float* __restrict__ x2){
    int mt = blockIdx.x, b = blockIdx.y;
    int i0 = mt*64;
    int tid = threadIdx.x, wave=tid>>6, lane=tid&63, quad=lane>>4, l16=lane&15;
    __shared__ __align__(16) unsigned short Uh[64*SR], Ul[64*SR];
    __shared__ __align__(16) unsigned short Wh[128*SR], Wo[128*SR];
    f32x4 zero = {0.f,0.f,0.f,0.f};
    f32x4 acc[8];
    #pragma unroll
    for(int nt=0;nt<8;nt++) acc[nt]=zero;
    for(int ph=0; ph<2; ph++){
        if(ph) __syncthreads();
        {
            int k = tid>>2, n0 = (tid&3)*32;
            for(int j=0;j<32;j++){
                float w = Wx2[(ph*64 + k)*128 + n0 + j];
                unsigned short hh = f2b(w);
                Wh[(n0+j)*SR + k] = hh;
                Wo[(n0+j)*SR + k] = f2b(w - b2f(hh));
            }
            int i = tid>>2, c0 = (tid&3)*16;
            const float* src = (ph ? ub : ua) + (((size_t)b<<10)+i0+i)*64 + c0;
            #pragma unroll
            for(int j=0;j<4;j++){
                float4 v = *(const float4*)(src + j*4);
                float vv[4] = {v.x, v.y, v.z, v.w};
                #pragma unroll
                for(int t=0;t<4;t++){
                    unsigned short hh = f2b(vv[t]);
                    Uh[i*SR + c0 + j*4 + t] = hh;
                    Ul[i*SR + c0 + j*4 + t] = f2b(vv[t] - b2f(hh));
                }
            }
        }
        __syncthreads();
        #pragma unroll
        for(int kc=0;kc<2;kc++){
            bf16x8 ah = *(const bf16x8*)&Uh[(wave*16+l16)*SR + kc*32 + quad*8];
            bf16x8 al = *(const bf16x8*)&Ul[(wave*16+l16)*SR + kc*32 + quad*8];
            #pragma unroll
            for(int nt=0;nt<8;nt++){
                bf16x8 bh = *(const bf16x8*)&Wh[(nt*16+l16)*SR + kc*32 + quad*8];
                bf16x8 bl = *(const bf16x8*)&Wo[(nt*16+l16)*SR + kc*32 + quad*8];
                acc[nt] = mfma16(ah, bh, acc[nt]);
                acc[nt] = mfma16(ah, bl, acc[nt]);
                acc[nt] = mfma16(al, bh, acc[nt]);
            }
        }
    }
    int gi = i0 + wave*16 + quad*4;
    #pragma unroll
    for(int nt=0;nt<8;nt++){
        int h = nt*16 + l16;
        #pragma unroll
        for(int rr=0;rr<4;rr++)
            x2[(((size_t)b<<10)+gi+rr)*128 + h] = acc[nt][rr];
    }
}

// ---------------- T2 reduce + epilogue (hi/lo MFMA, 2 K-phases) --------------------------
template<bool LAST>
__global__ __launch_bounds__(256) void reduce2_k(const float* __restrict__ partial,
        const float* __restrict__ Wl2, const float* __restrict__ x2,
        const float* __restrict__ We2, const float* __restrict__ WQ,
        unsigned short* __restrict__ Bnext, float* __restrict__ out){
    int mt = blockIdx.x, b = blockIdx.y;
    int i0 = mt*64;
    int tid = threadIdx.x, wave=tid>>6, lane=tid&63, quad=lane>>4, l16=lane&15;
    __shared__ __align__(16) unsigned short Lh[64*SR], Ll[64*SR];
    __shared__ __align__(16) unsigned short Wh[128*SR], Wo[128*SR];
    __shared__ float red[4];
    f32x4 zero = {0.f,0.f,0.f,0.f};
    f32x4 acc[8];
    #pragma unroll
    for(int nt=0;nt<8;nt++) acc[nt]=zero;
    for(int ph=0; ph<2; ph++){
        if(ph) __syncthreads();
        {
            int k = tid>>2, n0 = (tid&3)*32;
            for(int j=0;j<32;j++){
                float w = Wl2[(ph*64 + k)*128 + n0 + j];
                unsigned short hh = f2b(w);
                Wh[(n0+j)*SR + k] = hh;
                Wo[(n0+j)*SR + k] = f2b(w - b2f(hh));
            }
            int i = tid>>2, h0 = (tid&3)*16;
            const float* pp = partial + (((size_t)b<<10)+i0+i)*128 + ph*64 + h0;
            const size_t kss = (size_t)BATCH*1024*128;
            #pragma unroll
            for(int j=0;j<4;j++){
                float4 v0 = *(const float4*)(pp + j*4);
                float4 v1 = *(const float4*)(pp + kss + j*4);
                float4 v2 = *(const float4*)(pp + 2*kss + j*4);
                float4 v3 = *(const float4*)(pp + 3*kss + j*4);
                float vv[4] = {v0.x+v1.x+v2.x+v3.x, v0.y+v1.y+v2.y+v3.y,
                               v0.z+v1.z+v2.z+v3.z, v0.w+v1.w+v2.w+v3.w};
                #pragma unroll
                for(int t=0;t<4;t++){
                    unsigned short hh = f2b(vv[t]);
                    Lh[i*SR + h0 + j*4 + t] = hh;
                    Ll[i*SR + h0 + j*4 + t] = f2b(vv[t] - b2f(hh));
                }
            }
        }
        __syncthreads();
        #pragma unroll
        for(int kc=0;kc<2;kc++){
            bf16x8 ah = *(const bf16x8*)&Lh[(wave*16+l16)*SR + kc*32 + quad*8];
            bf16x8 al = *(const bf16x8*)&Ll[(wave*16+l16)*SR + kc*32 + quad*8];
            #pragma unroll
            for(int nt=0;nt<8;nt++){
                bf16x8 bh = *(const bf16x8*)&Wh[(nt*16+l16)*SR + kc*32 + quad*8];
                bf16x8 bl = *(const bf16x8*)&Wo[(nt*16+l16)*SR + kc*32 + quad*8];
                acc[nt] = mfma16(ah, bh, acc[nt]);
                acc[nt] = mfma16(ah, bl, acc[nt]);
                acc[nt] = mfma16(al, bh, acc[nt]);
            }
        }
    }
    int gi = i0 + wave*16 + quad*4;
    float qp = 0.f;
    #pragma unroll
    for(int nt=0;nt<8;nt++){
        int h = nt*16 + l16;
        float g[4];
        #pragma unroll
        for(int rr=0;rr<4;rr++)
            g[rr] = fmaxf(acc[nt][rr] + x2[(((size_t)b<<10)+gi+rr)*128 + h], 0.f);
        if(!LAST){
            float we = We2[h];
            float we2v = we*we;
            float q1 = C1f*we, q2 = C3f*we*we2v, q3 = C5f*we*we2v*we2v;
            ushort4 w0,w1,w2,w3;
            #pragma unroll
            for(int rr=0;rr<4;rr++){
                bool pad = (gi+rr == 1023);
                ((unsigned short*)&w0)[rr] = pad?(unsigned short)0:f2b(0.5f*g[rr]);
                ((unsigned short*)&w1)[rr] = pad?(unsigned short)0:f2b(q1*g[rr]);
                ((unsigned short*)&w2)[rr] = pad?(unsigned short)0:f2b(q2*g[rr]);
                ((unsigned short*)&w3)[rr] = pad?(unsigned short)0:f2b(q3*g[rr]);
            }
            size_t base = ((size_t)(b*128 + h))*KTOT + gi;
            *(ushort4*)&Bnext[base]      = w0;
            *(ushort4*)&Bnext[base+1024] = w1;
            *(ushort4*)&Bnext[base+2048] = w2;
            *(ushort4*)&Bnext[base+3072] = w3;
        } else {
            float wq = WQ[h];
            #pragma unroll
            for(int rr=0;rr<4;rr++) qp = fmaf(g[rr], wq, qp);
        }
    }
    if(LAST){
        for(int o=32;o>0;o>>=1) qp += __shfl_xor(qp,o,64);
        if(lane==0) red[wave]=qp;
        __syncthreads();
        if(tid==0) atomicAdd(&out[b], red[0]+red[1]+red[2]+red[3]);
    }
}

// ---------------- host launch ------------------------------------------------------------
extern "C" void kernel_launch(void* const* d_in, const int* in_sizes, int n_in,
                              void* d_out, int out_size, void* d_ws, size_t ws_size,
                              hipStream_t stream){
    (void)in_sizes; (void)n_in; (void)out_size; (void)ws_size;
    const float* xs   = (const float*)d_in[0];
    const float* ap   = (const float*)d_in[1];
    const float* act  = (const float*)d_in[2];
    const float* edge = (const float*)d_in[3];
    const float* avail= (const float*)d_in[4];
    const float* ua0  = (const float*)d_in[5];
    const float* g0   = (const float*)d_in[7];
    const float* W1p  = (const float*)d_in[8];
    const float* W2p  = (const float*)d_in[9];
    const float* Wx1a = (const float*)d_in[10];
    const float* We1a = (const float*)d_in[11];
    const float* Wl1a = (const float*)d_in[12];
    const float* Wx1b = (const float*)d_in[13];
    const float* Wl1b = (const float*)d_in[15];
    const float* Wx2  = (const float*)d_in[16];
    const float* We2  = (const float*)d_in[17];
    const float* Wl2  = (const float*)d_in[18];
    const float* WQ   = (const float*)d_in[19];
    float* out = (float*)d_out;

    char* ws = (char*)d_ws;
    // region 1: A' (persistent through all iterations): 16*1024*4096*2 = 134,217,728 B
    unsigned short* Abuf = (unsigned short*)ws;
    char* r2 = ws + 134217728;
    // P/D (fp16) live only until abuild; aliased with GEMM-phase buffers after:
    unsigned short* Pbuf = (unsigned short*)r2;                      // 33,521,664
    unsigned short* Dbuf = (unsigned short*)(r2 + 33521664);         // 33,521,664
    unsigned short* BT1a = (unsigned short*)r2;                      //  8,388,608
    unsigned short* BT1b = (unsigned short*)(r2 + 8388608);          //  8,388,608
    unsigned short* BT2a = (unsigned short*)(r2 + 16777216);         // 16,777,216
    unsigned short* BT2b = (unsigned short*)(r2 + 33554432);         // 16,777,216
    float* partial       = (float*)(r2 + 50331648);                  // 33,554,432
    float* uaB           = (float*)(r2 + 83886080);                  //  4,194,304
    float* ubB           = (float*)(r2 + 88080384);                  //  4,194,304
    float* x2B           = (float*)(r2 + 92274688);                  //  8,388,608
    float* xaB           = (float*)(r2 + 100663296);                 //     65,536
    unsigned short* BT1[2] = {BT1a, BT1b};
    unsigned short* BT2[2] = {BT2a, BT2b};

    hipMemsetAsync(d_out, 0, BATCH*sizeof(float), stream);
    xa_k<<<64,256,0,stream>>>(xs, ap, act, xaB);
    presence_k<<<dim3(CITIES,BATCH),256,0,stream>>>(edge, W1p, W2p, avail, Pbuf, Dbuf);
    abuild_k<<<dim3(32,32,BATCH),256,0,stream>>>(Pbuf, Dbuf, Abuf);
    binit_k<<<dim3(16,64,BATCH),256,0,stream>>>(ua0, We1a, BT1[0], 64);
    for(int it=0; it<5; it++){
        gemm_k<64><<<dim3(8,BATCH,4),256,0,stream>>>(Abuf, BT1[it&1], partial);
        if(it<4)
            reduce1_k<false><<<dim3(16,BATCH),256,0,stream>>>(partial, Wl1a, Wl1b,
                Wx1a, Wx1b, We1a, xaB, BT1[(it+1)&1], uaB, ubB);
        else
            reduce1_k<true><<<dim3(16,BATCH),256,0,stream>>>(partial, Wl1a, Wl1b,
                Wx1a, Wx1b, We1a, xaB, BT1[(it+1)&1], uaB, ubB);
    }
    x2_k<<<dim3(16,BATCH),256,0,stream>>>(uaB, ubB, Wx2, x2B);
    binit_k<<<dim3(16,128,BATCH),256,0,stream>>>(g0, We2, BT2[0], 128);
    for(int it=0; it<5; it++){
        gemm_k<128><<<dim3(8,BATCH,4),256,0,stream>>>(Abuf, BT2[it&1], partial);
        if(it<4)
            reduce2_k<false><<<dim3(16,BATCH),256,0,stream>>>(partial, Wl2, x2B,
                We2, WQ, BT2[(it+1)&1], out);
        else
            reduce2_k<true><<<dim3(16,BATCH),256,0,stream>>>(partial, Wl2, x2B,
                We2, WQ, BT2[(it+1)&1], out);
    }
}

// Round 3
// 1063.703 us; speedup vs baseline: 1.3085x; 1.3085x over previous
//
#include <hip/hip_runtime.h>

// ---- problem constants ----
#define BATCH 16
#define RB    8
#define CITIES 1023
#define NODES 1024
#define HDIM  64
#define H2DIM 128
#define KTOT  4096          // 4 poly terms * 1024 (c padded to 1024)
#define KCH   1024          // split-K chunk (x4)
#define KSTEPS 32           // 1024/32

// sigmoid(x) ~= 0.5 + C1*x + C3*x^3 + C5*x^5 on [-1,1], max err ~4e-6
#define C1f 0.24998145f
#define C3f (-0.02068089f)
#define C5f 0.00176243f

typedef __bf16    bf16x8 __attribute__((ext_vector_type(8)));
typedef _Float16  f16x8  __attribute__((ext_vector_type(8)));
typedef float     f32x4  __attribute__((ext_vector_type(4)));

__device__ __forceinline__ f32x4 mfma16(bf16x8 a, bf16x8 b, f32x4 c){
    return __builtin_amdgcn_mfma_f32_16x16x32_bf16(a, b, c, 0, 0, 0);
}
__device__ __forceinline__ f32x4 mfma16h(f16x8 a, f16x8 b, f32x4 c){
    return __builtin_amdgcn_mfma_f32_16x16x32_f16(a, b, c, 0, 0, 0);
}
__device__ __forceinline__ unsigned short f2b(float f){
    __bf16 b = (__bf16)f;
    return __builtin_bit_cast(unsigned short, b);
}
__device__ __forceinline__ float b2f(unsigned short u){
    unsigned int t = ((unsigned int)u) << 16;
    return __builtin_bit_cast(float, t);
}
__device__ __forceinline__ unsigned short f2h(float f){
    _Float16 h = (_Float16)f;
    return __builtin_bit_cast(unsigned short, h);
}
__device__ __forceinline__ float h2f(unsigned short u){
    return (float)__builtin_bit_cast(_Float16, u);
}
// async global->LDS, 16B per lane; LDS dest must be wave-uniform base + lane*16
__device__ __forceinline__ void async16(const void* g, void* l){
    __builtin_amdgcn_global_load_lds(
        (const __attribute__((address_space(1))) unsigned int*)g,
        (__attribute__((address_space(3))) unsigned int*)l, 16, 0, 0);
}

// ---------------- kernel: x_a[b,n] = max_r x_a_state*(assign_prev+action) ----------------
__global__ __launch_bounds__(256) void xa_k(const float* __restrict__ xs,
        const float* __restrict__ ap, const float* __restrict__ act,
        float* __restrict__ xa){
    int idx = blockIdx.x*256 + threadIdx.x;       // 16384
    int b = idx >> 10, n = idx & 1023;
    float m = -1e30f;
    #pragma unroll
    for(int r=0;r<RB;r++){
        size_t o = (((size_t)b*RB + r)<<10) + n;
        m = fmaxf(m, xs[o]*(ap[o]+act[o]));
    }
    xa[idx] = m;
}

// ---------------- presence MLP + softmax over n; writes p,d (fp16, [b][c][n]) ------------
// h-loop OUTER, 4 points per thread in registers: 64 LDS b128 reads/thread total,
// each amortized over 20 VALU ops (vs 256 reads w/ 4-5 VALU each before).
__global__ __launch_bounds__(256) void presence_k(const float* __restrict__ edge,
        const float* __restrict__ W1, const float* __restrict__ W2,
        const float* __restrict__ avail,
        unsigned short* __restrict__ P, unsigned short* __restrict__ D){
    int c = blockIdx.x, b = blockIdx.y;
    int tid = threadIdx.x;
    __shared__ float4 Wl[64];
    __shared__ float red[4];
    if(tid < 64) Wl[tid] = make_float4(W1[tid], W1[64+tid], W1[128+tid], W2[tid]);
    __syncthreads();
    float e0[4], e1[4], e2[4], acc[4];
    size_t ebase = (((size_t)b*CITIES + c)<<10)*3;
    #pragma unroll
    for(int j=0;j<4;j++){
        int n = tid + j*256;
        size_t ea = ebase + (size_t)n*3;
        e0[j]=edge[ea]; e1[j]=edge[ea+1]; e2[j]=edge[ea+2];
        acc[j]=0.f;
    }
    #pragma unroll 8
    for(int h=0;h<64;h++){
        float4 w = Wl[h];
        #pragma unroll
        for(int j=0;j<4;j++){
            float a = fmaf(e0[j],w.x, fmaf(e1[j],w.y, e2[j]*w.z));
            acc[j] = fmaf(fmaxf(a,0.f), w.w, acc[j]);
        }
    }
    float lg[4], ex[4];
    #pragma unroll
    for(int j=0;j<4;j++){
        int n = tid + j*256;
        float h2 = fmaxf(acc[j], 0.f);             // relu; /TAU with TAU=1
        float mk = (n==c) ? 0.f : avail[(b<<10)+n];
        lg[j] = h2*mk - (1.f-mk)*1e10f;
    }
    int wv = tid>>6, ln = tid&63;
    float mx = fmaxf(fmaxf(lg[0],lg[1]), fmaxf(lg[2],lg[3]));
    for(int o=32;o>0;o>>=1) mx = fmaxf(mx, __shfl_xor(mx,o,64));
    if(ln==0) red[wv]=mx;
    __syncthreads();
    mx = fmaxf(fmaxf(red[0],red[1]), fmaxf(red[2],red[3]));
    __syncthreads();
    float s = 0.f;
    for(int j=0;j<4;j++){ ex[j] = expf(lg[j]-mx); s += ex[j]; }
    for(int o=32;o>0;o>>=1) s += __shfl_xor(s,o,64);
    if(ln==0) red[wv]=s;
    __syncthreads();
    s = red[0]+red[1]+red[2]+red[3];
    float inv = 1.f/s;
    size_t pbase = ((size_t)b*CITIES + c)<<10;
    #pragma unroll
    for(int j=0;j<4;j++){
        int n = tid + j*256;
        P[pbase+n] = f2h(ex[j]*inv);
        D[pbase+n] = f2h(e0[j]);
    }
}

// ------- build A' [b][i][4*1024] fp16 = {p, p*d, p*d^3, p*d^5} transposed ----------------
__global__ __launch_bounds__(256) void abuild_k(const unsigned short* __restrict__ P,
        const unsigned short* __restrict__ D, unsigned short* __restrict__ A){
    int ct = blockIdx.x, nt = blockIdx.y, b = blockIdx.z;
    int tid = threadIdx.x;
    __shared__ unsigned short Pt[32][36];
    __shared__ unsigned short Dt[32][36];
    {
        int crow = tid>>3, ng = (tid&7)<<2;
        int c = ct*32 + crow;
        if(c < CITIES){
            size_t o = (((size_t)b*CITIES + c)<<10) + nt*32 + ng;
            *(ushort4*)&Pt[crow][ng] = *(const ushort4*)&P[o];
            *(ushort4*)&Dt[crow][ng] = *(const ushort4*)&D[o];
        } else {
            ushort4 z; z.x=0;z.y=0;z.z=0;z.w=0;
            *(ushort4*)&Pt[crow][ng] = z;
            *(ushort4*)&Dt[crow][ng] = z;
        }
    }
    __syncthreads();
    int nrow = tid>>3, cg = (tid&7)<<2;
    ushort4 w0, w1, w2, w3;
    #pragma unroll
    for(int j=0;j<4;j++){
        float p = h2f(Pt[cg+j][nrow]);
        float d = h2f(Dt[cg+j][nrow]);
        float d2 = d*d, d3 = d2*d, d5 = d3*d2;
        ((unsigned short*)&w0)[j] = f2h(p);
        ((unsigned short*)&w1)[j] = f2h(p*d);
        ((unsigned short*)&w2)[j] = f2h(p*d3);
        ((unsigned short*)&w3)[j] = f2h(p*d5);
    }
    size_t abase = ((size_t)(b<<10) + nt*32 + nrow)*KTOT + ct*32 + cg;
    *(ushort4*)&A[abase]      = w0;
    *(ushort4*)&A[abase+1024] = w1;
    *(ushort4*)&A[abase+2048] = w2;
    *(ushort4*)&A[abase+3072] = w3;
}

// ---------------- initial B'^T [b][h][kc] = q_k(h) * U0[b][c][h] (fp16) ------------------
__global__ __launch_bounds__(256) void binit_k(const float* __restrict__ U0,
        const float* __restrict__ We, unsigned short* __restrict__ BT, int nout){
    int kc = blockIdx.x*256 + threadIdx.x;   // 0..4095
    int h = blockIdx.y, b = blockIdx.z;
    int k = kc >> 10, c = kc & 1023;
    float we = We[h];
    float we2 = we*we;
    float q = (k==0) ? 0.5f : (k==1 ? C1f*we : (k==2 ? C3f*we*we2 : C5f*we*we2*we2));
    float u = (c < CITIES) ? U0[(((size_t)b<<10) + c)*nout + h] : 0.f;
    BT[((size_t)(b*nout + h))*KTOT + kc] = f2h(q*u);
}

// ---------------- main GEMM (fp16): partial[ks][b][i][h] = A'@B' chunk -------------------
// staging via global_load_lds width=16; LDS dest offsets are exactly tid*16 bytes.
template<int NOUT>
__global__ __launch_bounds__(256) void gemm_k(const unsigned short* __restrict__ Ap,
        const unsigned short* __restrict__ BT, float* __restrict__ partial){
    int mt = blockIdx.x, b = blockIdx.y, ks = blockIdx.z;
    int tid = threadIdx.x;
    int wave = tid>>6, lane = tid&63, quad = lane>>4, l16 = lane&15;
    __shared__ __align__(16) unsigned short At[128*32];
    __shared__ __align__(16) unsigned short Bt[NOUT*32];
    f32x4 zero = {0.f,0.f,0.f,0.f};
    f32x4 acc[2][NOUT/16];
    #pragma unroll
    for(int s=0;s<2;s++)
        #pragma unroll
        for(int nt=0;nt<NOUT/16;nt++) acc[s][nt] = zero;

    int r = tid>>2, cg = (tid&3)<<3;
    const unsigned short* ga0 = Ap + ((size_t)(b<<10) + mt*128 + r)*KTOT + ks*KCH + cg;
    const unsigned short* ga1 = ga0 + (size_t)64*KTOT;
    const unsigned short* gb0 = BT + ((size_t)b*NOUT + r)*KTOT + ks*KCH + cg;
    const unsigned short* gb1 = gb0 + (size_t)64*KTOT;
    unsigned short* la0 = At + tid*8;          // byte off = tid*16  (row r,   cols cg)
    unsigned short* la1 = At + 2048 + tid*8;   // row r+64
    unsigned short* lb0 = Bt + tid*8;
    unsigned short* lb1 = Bt + 2048 + tid*8;   // only NOUT==128

    for(int kk=0;kk<KSTEPS;kk++){
        __syncthreads();
        async16(ga0, la0);
        async16(ga1, la1);
        async16(gb0, lb0);
        if(NOUT == 128) async16(gb1, lb1);
        ga0 += 32; ga1 += 32; gb0 += 32; gb1 += 32;
        __syncthreads();
        f16x8 a0 = *(const f16x8*)&At[(wave*32      + l16)*32 + quad*8];
        f16x8 a1 = *(const f16x8*)&At[(wave*32 + 16 + l16)*32 + quad*8];
        #pragma unroll
        for(int nt=0; nt<NOUT/16; nt++){
            f16x8 bf = *(const f16x8*)&Bt[(nt*16 + l16)*32 + quad*8];
            acc[0][nt] = mfma16h(a0, bf, acc[0][nt]);
            acc[1][nt] = mfma16h(a1, bf, acc[1][nt]);
        }
    }
    float* pp = partial + (((size_t)(ks*BATCH + b)<<10) + mt*128)*NOUT;
    #pragma unroll
    for(int s=0;s<2;s++)
        #pragma unroll
        for(int nt=0;nt<NOUT/16;nt++){
            int row = wave*32 + s*16 + quad*4;
            int col = nt*16 + l16;
            #pragma unroll
            for(int rr=0;rr<4;rr++)
                pp[(size_t)(row+rr)*NOUT + col] = acc[s][nt][rr];
        }
}

// ---- T1 reduce + epilogue: u = relu(l@W_l + x_a*W_x); emit next B' (fp16) ---------------
#define SR 72
template<bool LAST>
__global__ __launch_bounds__(256) void reduce1_k(const float* __restrict__ partial,
        const float* __restrict__ Wl1a, const float* __restrict__ Wl1b,
        const float* __restrict__ Wx1a, const float* __restrict__ Wx1b,
        const float* __restrict__ We1a, const float* __restrict__ xa,
        unsigned short* __restrict__ Bnext, float* __restrict__ ua, float* __restrict__ ub){
    int mt = blockIdx.x, b = blockIdx.y;
    int i0 = mt*64;
    int tid = threadIdx.x, wave=tid>>6, lane=tid&63, quad=lane>>4, l16=lane&15;
    __shared__ __align__(16) unsigned short Lh[64*SR], Ll[64*SR];
    __shared__ __align__(16) unsigned short Wh[64*SR], Wo[64*SR];
    {
        int k = tid>>2, n0 = (tid&3)*16;
        for(int j=0;j<16;j++){
            float w = Wl1a[k*64 + n0 + j];
            unsigned short hh = f2b(w);
            Wh[(n0+j)*SR + k] = hh;
            Wo[(n0+j)*SR + k] = f2b(w - b2f(hh));
        }
        int i = tid>>2, h0 = (tid&3)*16;
        const float* pp = partial + (((size_t)b<<10)+i0+i)*64 + h0;
        const size_t kss = (size_t)BATCH*1024*64;
        #pragma unroll
        for(int j=0;j<4;j++){
            float4 v0 = *(const float4*)(pp + j*4);
            float4 v1 = *(const float4*)(pp + kss + j*4);
            float4 v2 = *(const float4*)(pp + 2*kss + j*4);
            float4 v3 = *(const float4*)(pp + 3*kss + j*4);
            float vv[4] = {v0.x+v1.x+v2.x+v3.x, v0.y+v1.y+v2.y+v3.y,
                           v0.z+v1.z+v2.z+v3.z, v0.w+v1.w+v2.w+v3.w};
            #pragma unroll
            for(int t=0;t<4;t++){
                unsigned short hh = f2b(vv[t]);
                Lh[i*SR + h0 + j*4 + t] = hh;
                Ll[i*SR + h0 + j*4 + t] = f2b(vv[t] - b2f(hh));
            }
        }
    }
    __syncthreads();
    f32x4 zero = {0.f,0.f,0.f,0.f};
    f32x4 acc[4] = {zero,zero,zero,zero};
    #pragma unroll
    for(int kc=0;kc<2;kc++){
        bf16x8 ah = *(const bf16x8*)&Lh[(wave*16+l16)*SR + kc*32 + quad*8];
        bf16x8 al = *(const bf16x8*)&Ll[(wave*16+l16)*SR + kc*32 + quad*8];
        #pragma unroll
        for(int nt=0;nt<4;nt++){
            bf16x8 bh = *(const bf16x8*)&Wh[(nt*16+l16)*SR + kc*32 + quad*8];
            bf16x8 bl = *(const bf16x8*)&Wo[(nt*16+l16)*SR + kc*32 + quad*8];
            acc[nt] = mfma16(ah, bh, acc[nt]);
            acc[nt] = mfma16(ah, bl, acc[nt]);
            acc[nt] = mfma16(al, bh, acc[nt]);
        }
    }
    int gi = i0 + wave*16 + quad*4;
    float4 xav = *(const float4*)&xa[(b<<10) + gi];
    float xr[4] = {xav.x, xav.y, xav.z, xav.w};
    if(!LAST){
        #pragma unroll
        for(int nt=0;nt<4;nt++){
            int h = nt*16 + l16;
            float wx = Wx1a[h];
            float we = We1a[h];
            float we2 = we*we;
            float q1 = C1f*we, q2 = C3f*we*we2, q3 = C5f*we*we2*we2;
            ushort4 w0,w1,w2,w3;
            #pragma unroll
            for(int rr=0;rr<4;rr++){
                float u = fmaxf(acc[nt][rr] + xr[rr]*wx, 0.f);
                bool pad = (gi+rr == 1023);
                ((unsigned short*)&w0)[rr] = pad?(unsigned short)0:f2h(0.5f*u);
                ((unsigned short*)&w1)[rr] = pad?(unsigned short)0:f2h(q1*u);
                ((unsigned short*)&w2)[rr] = pad?(unsigned short)0:f2h(q2*u);
                ((unsigned short*)&w3)[rr] = pad?(unsigned short)0:f2h(q3*u);
            }
            size_t base = ((size_t)(b*64 + h))*KTOT + gi;
            *(ushort4*)&Bnext[base]      = w0;
            *(ushort4*)&Bnext[base+1024] = w1;
            *(ushort4*)&Bnext[base+2048] = w2;
            *(ushort4*)&Bnext[base+3072] = w3;
        }
    } else {
        #pragma unroll
        for(int nt=0;nt<4;nt++){
            int h = nt*16+l16; float wx = Wx1a[h];
            #pragma unroll
            for(int rr=0;rr<4;rr++)
                ua[(((size_t)b<<10)+gi+rr)*64 + h] = fmaxf(acc[nt][rr] + xr[rr]*wx, 0.f);
        }
        __syncthreads();
        { int k = tid>>2, n0 = (tid&3)*16;
          for(int j=0;j<16;j++){
              float w = Wl1b[k*64 + n0 + j];
              unsigned short hh = f2b(w);
              Wh[(n0+j)*SR + k] = hh;
              Wo[(n0+j)*SR + k] = f2b(w - b2f(hh));
          } }
        __syncthreads();
        f32x4 acc2[4] = {zero,zero,zero,zero};
        #pragma unroll
        for(int kc=0;kc<2;kc++){
            bf16x8 ah = *(const bf16x8*)&Lh[(wave*16+l16)*SR + kc*32 + quad*8];
            bf16x8 al = *(const bf16x8*)&Ll[(wave*16+l16)*SR + kc*32 + quad*8];
            #pragma unroll
            for(int nt=0;nt<4;nt++){
                bf16x8 bh = *(const bf16x8*)&Wh[(nt*16+l16)*SR + kc*32 + quad*8];
                bf16x8 bl = *(const bf16x8*)&Wo[(nt*16+l16)*SR + kc*32 + quad*8];
                acc2[nt] = mfma16(ah, bh, acc2[nt]);
                acc2[nt] = mfma16(ah, bl, acc2[nt]);
                acc2[nt] = mfma16(al, bh, acc2[nt]);
            }
        }
        #pragma unroll
        for(int nt=0;nt<4;nt++){
            int h = nt*16+l16; float wx = Wx1b[h];
            #pragma unroll
            for(int rr=0;rr<4;rr++)
                ub[(((size_t)b<<10)+gi+rr)*64 + h] = fmaxf(acc2[nt][rr] + xr[rr]*wx, 0.f);
        }
    }
}

// ---------------- x2 = concat(ua,ub) @ W_x_2  (hi/lo MFMA, 2 K-phases) -------------------
__global__ __launch_bounds__(256) void x2_k(const float* __restrict__ ua,
        const float* __restrict__ ub, const float* __restrict__ Wx2,
        float* __restrict__ x2){
    int mt = blockIdx.x, b = blockIdx.y;
    int i0 = mt*64;
    int tid = threadIdx.x, wave=tid>>6, lane=tid&63, quad=lane>>4, l16=lane&15;
    __shared__ __align__(16) unsigned short Uh[64*SR], Ul[64*SR];
    __shared__ __align__(16) unsigned short Wh[128*SR], Wo[128*SR];
    f32x4 zero = {0.f,0.f,0.f,0.f};
    f32x4 acc[8];
    #pragma unroll
    for(int nt=0;nt<8;nt++) acc[nt]=zero;
    for(int ph=0; ph<2; ph++){
        if(ph) __syncthreads();
        {
            int k = tid>>2, n0 = (tid&3)*32;
            for(int j=0;j<32;j++){
                float w = Wx2[(ph*64 + k)*128 + n0 + j];
                unsigned short hh = f2b(w);
                Wh[(n0+j)*SR + k] = hh;
                Wo[(n0+j)*SR + k] = f2b(w - b2f(hh));
            }
            int i = tid>>2, c0 = (tid&3)*16;
            const float* src = (ph ? ub : ua) + (((size_t)b<<10)+i0+i)*64 + c0;
            #pragma unroll
            for(int j=0;j<4;j++){
                float4 v = *(const float4*)(src + j*4);
                float vv[4] = {v.x, v.y, v.z, v.w};
                #pragma unroll
                for(int t=0;t<4;t++){
                    unsigned short hh = f2b(vv[t]);
                    Uh[i*SR + c0 + j*4 + t] = hh;
                    Ul[i*SR + c0 + j*4 + t] = f2b(vv[t] - b2f(hh));
                }
            }
        }
        __syncthreads();
        #pragma unroll
        for(int kc=0;kc<2;kc++){
            bf16x8 ah = *(const bf16x8*)&Uh[(wave*16+l16)*SR + kc*32 + quad*8];
            bf16x8 al = *(const bf16x8*)&Ul[(wave*16+l16)*SR + kc*32 + quad*8];
            #pragma unroll
            for(int nt=0;nt<8;nt++){
                bf16x8 bh = *(const bf16x8*)&Wh[(nt*16+l16)*SR + kc*32 + quad*8];
                bf16x8 bl = *(const bf16x8*)&Wo[(nt*16+l16)*SR + kc*32 + quad*8];
                acc[nt] = mfma16(ah, bh, acc[nt]);
                acc[nt] = mfma16(ah, bl, acc[nt]);
                acc[nt] = mfma16(al, bh, acc[nt]);
            }
        }
    }
    int gi = i0 + wave*16 + quad*4;
    #pragma unroll
    for(int nt=0;nt<8;nt++){
        int h = nt*16 + l16;
        #pragma unroll
        for(int rr=0;rr<4;rr++)
            x2[(((size_t)b<<10)+gi+rr)*128 + h] = acc[nt][rr];
    }
}

// ---------------- T2 reduce + epilogue (hi/lo MFMA, 2 K-phases) --------------------------
template<bool LAST>
__global__ __launch_bounds__(256) void reduce2_k(const float* __restrict__ partial,
        const float* __restrict__ Wl2, const float* __restrict__ x2,
        const float* __restrict__ We2, const float* __restrict__ WQ,
        unsigned short* __restrict__ Bnext, float* __restrict__ out){
    int mt = blockIdx.x, b = blockIdx.y;
    int i0 = mt*64;
    int tid = threadIdx.x, wave=tid>>6, lane=tid&63, quad=lane>>4, l16=lane&15;
    __shared__ __align__(16) unsigned short Lh[64*SR], Ll[64*SR];
    __shared__ __align__(16) unsigned short Wh[128*SR], Wo[128*SR];
    __shared__ float red[4];
    f32x4 zero = {0.f,0.f,0.f,0.f};
    f32x4 acc[8];
    #pragma unroll
    for(int nt=0;nt<8;nt++) acc[nt]=zero;
    for(int ph=0; ph<2; ph++){
        if(ph) __syncthreads();
        {
            int k = tid>>2, n0 = (tid&3)*32;
            for(int j=0;j<32;j++){
                float w = Wl2[(ph*64 + k)*128 + n0 + j];
                unsigned short hh = f2b(w);
                Wh[(n0+j)*SR + k] = hh;
                Wo[(n0+j)*SR + k] = f2b(w - b2f(hh));
            }
            int i = tid>>2, h0 = (tid&3)*16;
            const float* pp = partial + (((size_t)b<<10)+i0+i)*128 + ph*64 + h0;
            const size_t kss = (size_t)BATCH*1024*128;
            #pragma unroll
            for(int j=0;j<4;j++){
                float4 v0 = *(const float4*)(pp + j*4);
                float4 v1 = *(const float4*)(pp + kss + j*4);
                float4 v2 = *(const float4*)(pp + 2*kss + j*4);
                float4 v3 = *(const float4*)(pp + 3*kss + j*4);
                float vv[4] = {v0.x+v1.x+v2.x+v3.x, v0.y+v1.y+v2.y+v3.y,
                               v0.z+v1.z+v2.z+v3.z, v0.w+v1.w+v2.w+v3.w};
                #pragma unroll
                for(int t=0;t<4;t++){
                    unsigned short hh = f2b(vv[t]);
                    Lh[i*SR + h0 + j*4 + t] = hh;
                    Ll[i*SR + h0 + j*4 + t] = f2b(vv[t] - b2f(hh));
                }
            }
        }
        __syncthreads();
        #pragma unroll
        for(int kc=0;kc<2;kc++){
            bf16x8 ah = *(const bf16x8*)&Lh[(wave*16+l16)*SR + kc*32 + quad*8];
            bf16x8 al = *(const bf16x8*)&Ll[(wave*16+l16)*SR + kc*32 + quad*8];
            #pragma unroll
            for(int nt=0;nt<8;nt++){
                bf16x8 bh = *(const bf16x8*)&Wh[(nt*16+l16)*SR + kc*32 + quad*8];
                bf16x8 bl = *(const bf16x8*)&Wo[(nt*16+l16)*SR + kc*32 + quad*8];
                acc[nt] = mfma16(ah, bh, acc[nt]);
                acc[nt] = mfma16(ah, bl, acc[nt]);
                acc[nt] = mfma16(al, bh, acc[nt]);
            }
        }
    }
    int gi = i0 + wave*16 + quad*4;
    float qp = 0.f;
    #pragma unroll
    for(int nt=0;nt<8;nt++){
        int h = nt*16 + l16;
        float g[4];
        #pragma unroll
        for(int rr=0;rr<4;rr++)
            g[rr] = fmaxf(acc[nt][rr] + x2[(((size_t)b<<10)+gi+rr)*128 + h], 0.f);
        if(!LAST){
            float we = We2[h];
            float we2v = we*we;
            float q1 = C1f*we, q2 = C3f*we*we2v, q3 = C5f*we*we2v*we2v;
            ushort4 w0,w1,w2,w3;
            #pragma unroll
            for(int rr=0;rr<4;rr++){
                bool pad = (gi+rr == 1023);
                ((unsigned short*)&w0)[rr] = pad?(unsigned short)0:f2h(0.5f*g[rr]);
                ((unsigned short*)&w1)[rr] = pad?(unsigned short)0:f2h(q1*g[rr]);
                ((unsigned short*)&w2)[rr] = pad?(unsigned short)0:f2h(q2*g[rr]);
                ((unsigned short*)&w3)[rr] = pad?(unsigned short)0:f2h(q3*g[rr]);
            }
            size_t base = ((size_t)(b*128 + h))*KTOT + gi;
            *(ushort4*)&Bnext[base]      = w0;
            *(ushort4*)&Bnext[base+1024] = w1;
            *(ushort4*)&Bnext[base+2048] = w2;
            *(ushort4*)&Bnext[base+3072] = w3;
        } else {
            float wq = WQ[h];
            #pragma unroll
            for(int rr=0;rr<4;rr++) qp = fmaf(g[rr], wq, qp);
        }
    }
    if(LAST){
        for(int o=32;o>0;o>>=1) qp += __shfl_xor(qp,o,64);
        if(lane==0) red[wave]=qp;
        __syncthreads();
        if(tid==0) atomicAdd(&out[b], red[0]+red[1]+red[2]+red[3]);
    }
}

// ---------------- host launch ------------------------------------------------------------
extern "C" void kernel_launch(void* const* d_in, const int* in_sizes, int n_in,
                              void* d_out, int out_size, void* d_ws, size_t ws_size,
                              hipStream_t stream){
    (void)in_sizes; (void)n_in; (void)out_size; (void)ws_size;
    const float* xs   = (const float*)d_in[0];
    const float* ap   = (const float*)d_in[1];
    const float* act  = (const float*)d_in[2];
    const float* edge = (const float*)d_in[3];
    const float* avail= (const float*)d_in[4];
    const float* ua0  = (const float*)d_in[5];
    const float* g0   = (const float*)d_in[7];
    const float* W1p  = (const float*)d_in[8];
    const float* W2p  = (const float*)d_in[9];
    const float* Wx1a = (const float*)d_in[10];
    const float* We1a = (const float*)d_in[11];
    const float* Wl1a = (const float*)d_in[12];
    const float* Wx1b = (const float*)d_in[13];
    const float* Wl1b = (const float*)d_in[15];
    const float* Wx2  = (const float*)d_in[16];
    const float* We2  = (const float*)d_in[17];
    const float* Wl2  = (const float*)d_in[18];
    const float* WQ   = (const float*)d_in[19];
    float* out = (float*)d_out;

    char* ws = (char*)d_ws;
    // region 1: A' (persistent through all iterations): 16*1024*4096*2 = 134,217,728 B
    unsigned short* Abuf = (unsigned short*)ws;
    char* r2 = ws + 134217728;
    // P/D (fp16) live only until abuild; aliased with GEMM-phase buffers after:
    unsigned short* Pbuf = (unsigned short*)r2;                      // 33,521,664
    unsigned short* Dbuf = (unsigned short*)(r2 + 33521664);         // 33,521,664
    unsigned short* BT1a = (unsigned short*)r2;                      //  8,388,608
    unsigned short* BT1b = (unsigned short*)(r2 + 8388608);          //  8,388,608
    unsigned short* BT2a = (unsigned short*)(r2 + 16777216);         // 16,777,216
    unsigned short* BT2b = (unsigned short*)(r2 + 33554432);         // 16,777,216
    float* partial       = (float*)(r2 + 50331648);                  // 33,554,432
    float* uaB           = (float*)(r2 + 83886080);                  //  4,194,304
    float* ubB           = (float*)(r2 + 88080384);                  //  4,194,304
    float* x2B           = (float*)(r2 + 92274688);                  //  8,388,608
    float* xaB           = (float*)(r2 + 100663296);                 //     65,536
    unsigned short* BT1[2] = {BT1a, BT1b};
    unsigned short* BT2[2] = {BT2a, BT2b};

    hipMemsetAsync(d_out, 0, BATCH*sizeof(float), stream);
    xa_k<<<64,256,0,stream>>>(xs, ap, act, xaB);
    presence_k<<<dim3(CITIES,BATCH),256,0,stream>>>(edge, W1p, W2p, avail, Pbuf, Dbuf);
    abuild_k<<<dim3(32,32,BATCH),256,0,stream>>>(Pbuf, Dbuf, Abuf);
    binit_k<<<dim3(16,64,BATCH),256,0,stream>>>(ua0, We1a, BT1[0], 64);
    for(int it=0; it<5; it++){
        gemm_k<64><<<dim3(8,BATCH,4),256,0,stream>>>(Abuf, BT1[it&1], partial);
        if(it<4)
            reduce1_k<false><<<dim3(16,BATCH),256,0,stream>>>(partial, Wl1a, Wl1b,
                Wx1a, Wx1b, We1a, xaB, BT1[(it+1)&1], uaB, ubB);
        else
            reduce1_k<true><<<dim3(16,BATCH),256,0,stream>>>(partial, Wl1a, Wl1b,
                Wx1a, Wx1b, We1a, xaB, BT1[(it+1)&1], uaB, ubB);
    }
    x2_k<<<dim3(16,BATCH),256,0,stream>>>(uaB, ubB, Wx2, x2B);
    binit_k<<<dim3(16,128,BATCH),256,0,stream>>>(g0, We2, BT2[0], 128);
    for(int it=0; it<5; it++){
        gemm_k<128><<<dim3(8,BATCH,4),256,0,stream>>>(Abuf, BT2[it&1], partial);
        if(it<4)
            reduce2_k<false><<<dim3(16,BATCH),256,0,stream>>>(partial, Wl2, x2B,
                We2, WQ, BT2[(it+1)&1], out);
        else
            reduce2_k<true><<<dim3(16,BATCH),256,0,stream>>>(partial, Wl2, x2B,
                We2, WQ, BT2[(it+1)&1], out);
    }
}

// Round 4
// 936.104 us; speedup vs baseline: 1.4869x; 1.1363x over previous
//
#include <hip/hip_runtime.h>

// ---- problem constants ----
#define BATCH 16
#define RB    8
#define CITIES 1023
#define NODES 1024
#define HDIM  64
#define H2DIM 128
#define KTOT  3072          // 3 poly terms * 1024 (c padded to 1024)

// sigmoid(x) ~= 0.5 + C1*x + C3*x^3 on [-1,1], max err ~1.3e-4
#define C1f 0.24944119f
#define C3f (-0.01850586f)

typedef __bf16    bf16x8 __attribute__((ext_vector_type(8)));
typedef _Float16  f16x8  __attribute__((ext_vector_type(8)));
typedef float     f32x4  __attribute__((ext_vector_type(4)));

__device__ __forceinline__ f32x4 mfma16(bf16x8 a, bf16x8 b, f32x4 c){
    return __builtin_amdgcn_mfma_f32_16x16x32_bf16(a, b, c, 0, 0, 0);
}
__device__ __forceinline__ f32x4 mfma16h(f16x8 a, f16x8 b, f32x4 c){
    return __builtin_amdgcn_mfma_f32_16x16x32_f16(a, b, c, 0, 0, 0);
}
__device__ __forceinline__ unsigned short f2b(float f){
    __bf16 b = (__bf16)f;
    return __builtin_bit_cast(unsigned short, b);
}
__device__ __forceinline__ float b2f(unsigned short u){
    unsigned int t = ((unsigned int)u) << 16;
    return __builtin_bit_cast(float, t);
}
__device__ __forceinline__ unsigned short f2h(float f){
    _Float16 h = (_Float16)f;
    return __builtin_bit_cast(unsigned short, h);
}
__device__ __forceinline__ float h2f(unsigned short u){
    return (float)__builtin_bit_cast(_Float16, u);
}
__device__ __forceinline__ void async16(const void* g, void* l){
    __builtin_amdgcn_global_load_lds(
        (const __attribute__((address_space(1))) unsigned int*)g,
        (__attribute__((address_space(3))) unsigned int*)l, 16, 0, 0);
}

// ---------------- kernel: x_a[b,n] = max_r x_a_state*(assign_prev+action) ----------------
__global__ __launch_bounds__(256) void xa_k(const float* __restrict__ xs,
        const float* __restrict__ ap, const float* __restrict__ act,
        float* __restrict__ xa){
    int idx = blockIdx.x*256 + threadIdx.x;       // 16384
    int b = idx >> 10, n = idx & 1023;
    float m = -1e30f;
    #pragma unroll
    for(int r=0;r<RB;r++){
        size_t o = (((size_t)b*RB + r)<<10) + n;
        m = fmaxf(m, xs[o]*(ap[o]+act[o]));
    }
    xa[idx] = m;
}

// ---------------- presence MLP + softmax; 128 thr, 8 pts/thread in registers -------------
__global__ __launch_bounds__(128) void presence_k(const float* __restrict__ edge,
        const float* __restrict__ W1, const float* __restrict__ W2,
        const float* __restrict__ avail,
        unsigned short* __restrict__ P, unsigned short* __restrict__ D){
    int c = blockIdx.x, b = blockIdx.y;
    int tid = threadIdx.x;
    __shared__ float4 Wl[64];
    __shared__ float red[2];
    if(tid < 64) Wl[tid] = make_float4(W1[tid], W1[64+tid], W1[128+tid], W2[tid]);
    __syncthreads();
    float e0[8], e1[8], e2[8], acc[8];
    size_t ebase = (((size_t)b*CITIES + c)<<10)*3;
    #pragma unroll
    for(int j=0;j<8;j++){
        int n = tid + j*128;
        size_t ea = ebase + (size_t)n*3;
        e0[j]=edge[ea]; e1[j]=edge[ea+1]; e2[j]=edge[ea+2];
        acc[j]=0.f;
    }
    for(int h=0;h<64;h++){
        float4 w = Wl[h];
        #pragma unroll
        for(int j=0;j<8;j++){
            float a = fmaf(e0[j],w.x, fmaf(e1[j],w.y, e2[j]*w.z));
            acc[j] = fmaf(fmaxf(a,0.f), w.w, acc[j]);
        }
    }
    float lg[8], ex[8];
    #pragma unroll
    for(int j=0;j<8;j++){
        int n = tid + j*128;
        float h2 = fmaxf(acc[j], 0.f);             // relu; /TAU with TAU=1
        float mk = (n==c) ? 0.f : avail[(b<<10)+n];
        lg[j] = h2*mk - (1.f-mk)*1e10f;
    }
    int wv = tid>>6, ln = tid&63;
    float mx = -1e30f;
    #pragma unroll
    for(int j=0;j<8;j++) mx = fmaxf(mx, lg[j]);
    for(int o=32;o>0;o>>=1) mx = fmaxf(mx, __shfl_xor(mx,o,64));
    if(ln==0) red[wv]=mx;
    __syncthreads();
    mx = fmaxf(red[0],red[1]);
    __syncthreads();
    float s = 0.f;
    #pragma unroll
    for(int j=0;j<8;j++){ ex[j] = expf(lg[j]-mx); s += ex[j]; }
    for(int o=32;o>0;o>>=1) s += __shfl_xor(s,o,64);
    if(ln==0) red[wv]=s;
    __syncthreads();
    s = red[0]+red[1];
    float inv = 1.f/s;
    size_t pbase = ((size_t)b*CITIES + c)<<10;
    #pragma unroll
    for(int j=0;j<8;j++){
        int n = tid + j*128;
        P[pbase+n] = f2h(ex[j]*inv);
        D[pbase+n] = f2h(e0[j]);
    }
}

// ------- build A' [b][i][3*1024] fp16 = {p, p*d, p*d^3} transposed -----------------------
__global__ __launch_bounds__(256) void abuild_k(const unsigned short* __restrict__ P,
        const unsigned short* __restrict__ D, unsigned short* __restrict__ A){
    int ct = blockIdx.x, nt = blockIdx.y, b = blockIdx.z;
    int tid = threadIdx.x;
    __shared__ unsigned short Pt[32][36];
    __shared__ unsigned short Dt[32][36];
    {
        int crow = tid>>3, ng = (tid&7)<<2;
        int c = ct*32 + crow;
        if(c < CITIES){
            size_t o = (((size_t)b*CITIES + c)<<10) + nt*32 + ng;
            *(ushort4*)&Pt[crow][ng] = *(const ushort4*)&P[o];
            *(ushort4*)&Dt[crow][ng] = *(const ushort4*)&D[o];
        } else {
            ushort4 z; z.x=0;z.y=0;z.z=0;z.w=0;
            *(ushort4*)&Pt[crow][ng] = z;
            *(ushort4*)&Dt[crow][ng] = z;
        }
    }
    __syncthreads();
    int nrow = tid>>3, cg = (tid&7)<<2;
    ushort4 w0, w1, w2;
    #pragma unroll
    for(int j=0;j<4;j++){
        float p = h2f(Pt[cg+j][nrow]);
        float d = h2f(Dt[cg+j][nrow]);
        float d3 = d*d*d;
        ((unsigned short*)&w0)[j] = f2h(p);
        ((unsigned short*)&w1)[j] = f2h(p*d);
        ((unsigned short*)&w2)[j] = f2h(p*d3);
    }
    size_t abase = ((size_t)(b<<10) + nt*32 + nrow)*KTOT + ct*32 + cg;
    *(ushort4*)&A[abase]      = w0;
    *(ushort4*)&A[abase+1024] = w1;
    *(ushort4*)&A[abase+2048] = w2;
}

// ---------------- initial B'^T [b][h][kc] = q_k(h) * U0[b][c][h] (fp16) ------------------
__global__ __launch_bounds__(256) void binit_k(const float* __restrict__ U0,
        const float* __restrict__ We, unsigned short* __restrict__ BT, int nout){
    int kc = blockIdx.x*256 + threadIdx.x;   // 0..3071
    int h = blockIdx.y, b = blockIdx.z;
    int k = kc >> 10, c = kc & 1023;
    float we = We[h];
    float q = (k==0) ? 0.5f : (k==1 ? C1f*we : C3f*we*we*we);
    float u = (c < CITIES) ? U0[(((size_t)b<<10) + c)*nout + h] : 0.f;
    BT[((size_t)(b*nout + h))*KTOT + kc] = f2h(q*u);
}

// ---------------- main GEMM v2: BK=64, XOR-swizzled LDS, async16 staging -----------------
// partial[ks][b][i][h]; grid (1024/M, BATCH, KTOT/KCH)
template<int M, int NOUT, int KCH>
__global__ __launch_bounds__(256, 3) void gemm2_k(const unsigned short* __restrict__ Ap,
        const unsigned short* __restrict__ BT, float* __restrict__ partial){
    constexpr int KSTEPS = KCH/64;
    constexpr int AR = (M*64)/2048;      // A staging rounds (256 thr x 8 halves)
    constexpr int BR = (NOUT*64)/2048;
    constexpr int MT = M/64;             // m-tiles per wave (wave owns M/4 rows)
    constexpr int NT = NOUT/16;
    int mt = blockIdx.x, b = blockIdx.y, ks = blockIdx.z;
    int tid = threadIdx.x;
    int wave = tid>>6, lane = tid&63, quad = lane>>4, l16 = lane&15;
    __shared__ __align__(16) unsigned short At[M*64];
    __shared__ __align__(16) unsigned short Bt[NOUT*64];
    f32x4 acc[MT][NT];
    #pragma unroll
    for(int i=0;i<MT;i++)
        #pragma unroll
        for(int nt=0;nt<NT;nt++) acc[i][nt] = (f32x4){0.f,0.f,0.f,0.f};

    // staging pointers: linear idx -> (row, 16B-chunk); source chunk xor-swizzled by row&7
    const unsigned short* pa[AR];
    const unsigned short* pb[BR];
    #pragma unroll
    for(int rd=0; rd<AR; rd++){
        int idx = rd*256 + tid, r = idx>>3, ch = idx&7;
        pa[rd] = Ap + ((size_t)(b<<10) + mt*M + r)*KTOT + ks*KCH + ((ch ^ (r&7))<<3);
    }
    #pragma unroll
    for(int rd=0; rd<BR; rd++){
        int idx = rd*256 + tid, r = idx>>3, ch = idx&7;
        pb[rd] = BT + ((size_t)b*NOUT + r)*KTOT + ks*KCH + ((ch ^ (r&7))<<3);
    }
    int sw = (l16&7);
    for(int kk=0;kk<KSTEPS;kk++){
        __syncthreads();
        #pragma unroll
        for(int rd=0; rd<AR; rd++){ async16(pa[rd], At + rd*2048 + tid*8); pa[rd] += 64; }
        #pragma unroll
        for(int rd=0; rd<BR; rd++){ async16(pb[rd], Bt + rd*2048 + tid*8); pb[rd] += 64; }
        __syncthreads();
        #pragma unroll
        for(int kb=0; kb<2; kb++){
            f16x8 af[MT];
            #pragma unroll
            for(int i=0;i<MT;i++)
                af[i] = *(const f16x8*)&At[(wave*(M/4) + i*16 + l16)*64 + (((kb*4+quad)^sw)<<3)];
            #pragma unroll
            for(int nt=0;nt<NT;nt++){
                f16x8 bf = *(const f16x8*)&Bt[(nt*16 + l16)*64 + (((kb*4+quad)^sw)<<3)];
                #pragma unroll
                for(int i=0;i<MT;i++) acc[i][nt] = mfma16h(af[i], bf, acc[i][nt]);
            }
        }
    }
    float* pp = partial + (((size_t)(ks*BATCH + b)<<10) + mt*M)*NOUT;
    #pragma unroll
    for(int i=0;i<MT;i++)
        #pragma unroll
        for(int nt=0;nt<NT;nt++){
            int row = wave*(M/4) + i*16 + quad*4;
            int col = nt*16 + l16;
            #pragma unroll
            for(int rr=0;rr<4;rr++)
                pp[(size_t)(row+rr)*NOUT + col] = acc[i][nt][rr];
        }
}

// ---- T1 reduce + epilogue: u = relu(l@W_l + x_a*W_x); emit next B'. hi/lo 3-product ----
#define SR 72
#define NKS1 12
#define NKS2 6
template<bool LAST>
__global__ __launch_bounds__(256) void reduce1_k(const float* __restrict__ partial,
        const float* __restrict__ Wl1a, const float* __restrict__ Wl1b,
        const float* __restrict__ Wx1a, const float* __restrict__ Wx1b,
        const float* __restrict__ We1a, const float* __restrict__ xa,
        unsigned short* __restrict__ Bnext, float* __restrict__ ua, float* __restrict__ ub){
    int mt = blockIdx.x, b = blockIdx.y;
    int i0 = mt*64;
    int tid = threadIdx.x, wave=tid>>6, lane=tid&63, quad=lane>>4, l16=lane&15;
    __shared__ __align__(16) unsigned short Lh[64*SR], Ll[64*SR];
    __shared__ __align__(16) unsigned short Wh[64*SR], Wo[64*SR];
    {
        int k = tid>>2, n0 = (tid&3)*16;
        for(int j=0;j<16;j++){
            float w = Wl1a[k*64 + n0 + j];
            unsigned short hh = f2b(w);
            Wh[(n0+j)*SR + k] = hh;
            Wo[(n0+j)*SR + k] = f2b(w - b2f(hh));
        }
        int i = tid>>2, h0 = (tid&3)*16;
        const float* pp = partial + (((size_t)b<<10)+i0+i)*64 + h0;
        const size_t kss = (size_t)BATCH*1024*64;
        #pragma unroll
        for(int j=0;j<4;j++){
            float4 s = make_float4(0.f,0.f,0.f,0.f);
            #pragma unroll
            for(int ch=0; ch<NKS1; ch++){
                float4 v = *(const float4*)(pp + ch*kss + j*4);
                s.x+=v.x; s.y+=v.y; s.z+=v.z; s.w+=v.w;
            }
            float vv[4] = {s.x, s.y, s.z, s.w};
            #pragma unroll
            for(int t=0;t<4;t++){
                unsigned short hh = f2b(vv[t]);
                Lh[i*SR + h0 + j*4 + t] = hh;
                Ll[i*SR + h0 + j*4 + t] = f2b(vv[t] - b2f(hh));
            }
        }
    }
    __syncthreads();
    f32x4 zero = {0.f,0.f,0.f,0.f};
    f32x4 acc[4] = {zero,zero,zero,zero};
    #pragma unroll
    for(int kc=0;kc<2;kc++){
        bf16x8 ah = *(const bf16x8*)&Lh[(wave*16+l16)*SR + kc*32 + quad*8];
        bf16x8 al = *(const bf16x8*)&Ll[(wave*16+l16)*SR + kc*32 + quad*8];
        #pragma unroll
        for(int nt=0;nt<4;nt++){
            bf16x8 bh = *(const bf16x8*)&Wh[(nt*16+l16)*SR + kc*32 + quad*8];
            bf16x8 bl = *(const bf16x8*)&Wo[(nt*16+l16)*SR + kc*32 + quad*8];
            acc[nt] = mfma16(ah, bh, acc[nt]);
            acc[nt] = mfma16(ah, bl, acc[nt]);
            acc[nt] = mfma16(al, bh, acc[nt]);
        }
    }
    int gi = i0 + wave*16 + quad*4;
    float4 xav = *(const float4*)&xa[(b<<10) + gi];
    float xr[4] = {xav.x, xav.y, xav.z, xav.w};
    if(!LAST){
        #pragma unroll
        for(int nt=0;nt<4;nt++){
            int h = nt*16 + l16;
            float wx = Wx1a[h];
            float we = We1a[h];
            float q1 = C1f*we, q2 = C3f*we*we*we;
            ushort4 w0,w1,w2;
            #pragma unroll
            for(int rr=0;rr<4;rr++){
                float u = fmaxf(acc[nt][rr] + xr[rr]*wx, 0.f);
                bool pad = (gi+rr == 1023);
                ((unsigned short*)&w0)[rr] = pad?(unsigned short)0:f2h(0.5f*u);
                ((unsigned short*)&w1)[rr] = pad?(unsigned short)0:f2h(q1*u);
                ((unsigned short*)&w2)[rr] = pad?(unsigned short)0:f2h(q2*u);
            }
            size_t base = ((size_t)(b*64 + h))*KTOT + gi;
            *(ushort4*)&Bnext[base]      = w0;
            *(ushort4*)&Bnext[base+1024] = w1;
            *(ushort4*)&Bnext[base+2048] = w2;
        }
    } else {
        #pragma unroll
        for(int nt=0;nt<4;nt++){
            int h = nt*16+l16; float wx = Wx1a[h];
            #pragma unroll
            for(int rr=0;rr<4;rr++)
                ua[(((size_t)b<<10)+gi+rr)*64 + h] = fmaxf(acc[nt][rr] + xr[rr]*wx, 0.f);
        }
        __syncthreads();
        { int k = tid>>2, n0 = (tid&3)*16;
          for(int j=0;j<16;j++){
              float w = Wl1b[k*64 + n0 + j];
              unsigned short hh = f2b(w);
              Wh[(n0+j)*SR + k] = hh;
              Wo[(n0+j)*SR + k] = f2b(w - b2f(hh));
          } }
        __syncthreads();
        f32x4 acc2[4] = {zero,zero,zero,zero};
        #pragma unroll
        for(int kc=0;kc<2;kc++){
            bf16x8 ah = *(const bf16x8*)&Lh[(wave*16+l16)*SR + kc*32 + quad*8];
            bf16x8 al = *(const bf16x8*)&Ll[(wave*16+l16)*SR + kc*32 + quad*8];
            #pragma unroll
            for(int nt=0;nt<4;nt++){
                bf16x8 bh = *(const bf16x8*)&Wh[(nt*16+l16)*SR + kc*32 + quad*8];
                bf16x8 bl = *(const bf16x8*)&Wo[(nt*16+l16)*SR + kc*32 + quad*8];
                acc2[nt] = mfma16(ah, bh, acc2[nt]);
                acc2[nt] = mfma16(ah, bl, acc2[nt]);
                acc2[nt] = mfma16(al, bh, acc2[nt]);
            }
        }
        #pragma unroll
        for(int nt=0;nt<4;nt++){
            int h = nt*16+l16; float wx = Wx1b[h];
            #pragma unroll
            for(int rr=0;rr<4;rr++)
                ub[(((size_t)b<<10)+gi+rr)*64 + h] = fmaxf(acc2[nt][rr] + xr[rr]*wx, 0.f);
        }
    }
}

// ---------------- x2 = concat(ua,ub) @ W_x_2  (hi/lo MFMA, 2 K-phases) -------------------
__global__ __launch_bounds__(256) void x2_k(const float* __restrict__ ua,
        const float* __restrict__ ub, const float* __restrict__ Wx2,
        float* __restrict__ x2){
    int mt = blockIdx.x, b = blockIdx.y;
    int i0 = mt*64;
    int tid = threadIdx.x, wave=tid>>6, lane=tid&63, quad=lane>>4, l16=lane&15;
    __shared__ __align__(16) unsigned short Uh[64*SR], Ul[64*SR];
    __shared__ __align__(16) unsigned short Wh[128*SR], Wo[128*SR];
    f32x4 zero = {0.f,0.f,0.f,0.f};
    f32x4 acc[8];
    #pragma unroll
    for(int nt=0;nt<8;nt++) acc[nt]=zero;
    for(int ph=0; ph<2; ph++){
        if(ph) __syncthreads();
        {
            int k = tid>>2, n0 = (tid&3)*32;
            for(int j=0;j<32;j++){
                float w = Wx2[(ph*64 + k)*128 + n0 + j];
                unsigned short hh = f2b(w);
                Wh[(n0+j)*SR + k] = hh;
                Wo[(n0+j)*SR + k] = f2b(w - b2f(hh));
            }
            int i = tid>>2, c0 = (tid&3)*16;
            const float* src = (ph ? ub : ua) + (((size_t)b<<10)+i0+i)*64 + c0;
            #pragma unroll
            for(int j=0;j<4;j++){
                float4 v = *(const float4*)(src + j*4);
                float vv[4] = {v.x, v.y, v.z, v.w};
                #pragma unroll
                for(int t=0;t<4;t++){
                    unsigned short hh = f2b(vv[t]);
                    Uh[i*SR + c0 + j*4 + t] = hh;
                    Ul[i*SR + c0 + j*4 + t] = f2b(vv[t] - b2f(hh));
                }
            }
        }
        __syncthreads();
        #pragma unroll
        for(int kc=0;kc<2;kc++){
            bf16x8 ah = *(const bf16x8*)&Uh[(wave*16+l16)*SR + kc*32 + quad*8];
            bf16x8 al = *(const bf16x8*)&Ul[(wave*16+l16)*SR + kc*32 + quad*8];
            #pragma unroll
            for(int nt=0;nt<8;nt++){
                bf16x8 bh = *(const bf16x8*)&Wh[(nt*16+l16)*SR + kc*32 + quad*8];
                bf16x8 bl = *(const bf16x8*)&Wo[(nt*16+l16)*SR + kc*32 + quad*8];
                acc[nt] = mfma16(ah, bh, acc[nt]);
                acc[nt] = mfma16(ah, bl, acc[nt]);
                acc[nt] = mfma16(al, bh, acc[nt]);
            }
        }
    }
    int gi = i0 + wave*16 + quad*4;
    #pragma unroll
    for(int nt=0;nt<8;nt++){
        int h = nt*16 + l16;
        #pragma unroll
        for(int rr=0;rr<4;rr++)
            x2[(((size_t)b<<10)+gi+rr)*128 + h] = acc[nt][rr];
    }
}

// ---------------- T2 reduce + epilogue (hi/lo MFMA, 2 K-phases) --------------------------
template<bool LAST>
__global__ __launch_bounds__(256) void reduce2_k(const float* __restrict__ partial,
        const float* __restrict__ Wl2, const float* __restrict__ x2,
        const float* __restrict__ We2, const float* __restrict__ WQ,
        unsigned short* __restrict__ Bnext, float* __restrict__ out){
    int mt = blockIdx.x, b = blockIdx.y;
    int i0 = mt*64;
    int tid = threadIdx.x, wave=tid>>6, lane=tid&63, quad=lane>>4, l16=lane&15;
    __shared__ __align__(16) unsigned short Lh[64*SR], Ll[64*SR];
    __shared__ __align__(16) unsigned short Wh[128*SR], Wo[128*SR];
    __shared__ float red[4];
    f32x4 zero = {0.f,0.f,0.f,0.f};
    f32x4 acc[8];
    #pragma unroll
    for(int nt=0;nt<8;nt++) acc[nt]=zero;
    for(int ph=0; ph<2; ph++){
        if(ph) __syncthreads();
        {
            int k = tid>>2, n0 = (tid&3)*32;
            for(int j=0;j<32;j++){
                float w = Wl2[(ph*64 + k)*128 + n0 + j];
                unsigned short hh = f2b(w);
                Wh[(n0+j)*SR + k] = hh;
                Wo[(n0+j)*SR + k] = f2b(w - b2f(hh));
            }
            int i = tid>>2, h0 = (tid&3)*16;
            const float* pp = partial + (((size_t)b<<10)+i0+i)*128 + ph*64 + h0;
            const size_t kss = (size_t)BATCH*1024*128;
            #pragma unroll
            for(int j=0;j<4;j++){
                float4 s = make_float4(0.f,0.f,0.f,0.f);
                #pragma unroll
                for(int ch=0; ch<NKS2; ch++){
                    float4 v = *(const float4*)(pp + ch*kss + j*4);
                    s.x+=v.x; s.y+=v.y; s.z+=v.z; s.w+=v.w;
                }
                float vv[4] = {s.x, s.y, s.z, s.w};
                #pragma unroll
                for(int t=0;t<4;t++){
                    unsigned short hh = f2b(vv[t]);
                    Lh[i*SR + h0 + j*4 + t] = hh;
                    Ll[i*SR + h0 + j*4 + t] = f2b(vv[t] - b2f(hh));
                }
            }
        }
        __syncthreads();
        #pragma unroll
        for(int kc=0;kc<2;kc++){
            bf16x8 ah = *(const bf16x8*)&Lh[(wave*16+l16)*SR + kc*32 + quad*8];
            bf16x8 al = *(const bf16x8*)&Ll[(wave*16+l16)*SR + kc*32 + quad*8];
            #pragma unroll
            for(int nt=0;nt<8;nt++){
                bf16x8 bh = *(const bf16x8*)&Wh[(nt*16+l16)*SR + kc*32 + quad*8];
                bf16x8 bl = *(const bf16x8*)&Wo[(nt*16+l16)*SR + kc*32 + quad*8];
                acc[nt] = mfma16(ah, bh, acc[nt]);
                acc[nt] = mfma16(ah, bl, acc[nt]);
                acc[nt] = mfma16(al, bh, acc[nt]);
            }
        }
    }
    int gi = i0 + wave*16 + quad*4;
    float qp = 0.f;
    #pragma unroll
    for(int nt=0;nt<8;nt++){
        int h = nt*16 + l16;
        float g[4];
        #pragma unroll
        for(int rr=0;rr<4;rr++)
            g[rr] = fmaxf(acc[nt][rr] + x2[(((size_t)b<<10)+gi+rr)*128 + h], 0.f);
        if(!LAST){
            float we = We2[h];
            float q1 = C1f*we, q2 = C3f*we*we*we;
            ushort4 w0,w1,w2;
            #pragma unroll
            for(int rr=0;rr<4;rr++){
                bool pad = (gi+rr == 1023);
                ((unsigned short*)&w0)[rr] = pad?(unsigned short)0:f2h(0.5f*g[rr]);
                ((unsigned short*)&w1)[rr] = pad?(unsigned short)0:f2h(q1*g[rr]);
                ((unsigned short*)&w2)[rr] = pad?(unsigned short)0:f2h(q2*g[rr]);
            }
            size_t base = ((size_t)(b*128 + h))*KTOT + gi;
            *(ushort4*)&Bnext[base]      = w0;
            *(ushort4*)&Bnext[base+1024] = w1;
            *(ushort4*)&Bnext[base+2048] = w2;
        } else {
            float wq = WQ[h];
            #pragma unroll
            for(int rr=0;rr<4;rr++) qp = fmaf(g[rr], wq, qp);
        }
    }
    if(LAST){
        for(int o=32;o>0;o>>=1) qp += __shfl_xor(qp,o,64);
        if(lane==0) red[wave]=qp;
        __syncthreads();
        if(tid==0) atomicAdd(&out[b], red[0]+red[1]+red[2]+red[3]);
    }
}

// ---------------- host launch ------------------------------------------------------------
extern "C" void kernel_launch(void* const* d_in, const int* in_sizes, int n_in,
                              void* d_out, int out_size, void* d_ws, size_t ws_size,
                              hipStream_t stream){
    (void)in_sizes; (void)n_in; (void)out_size; (void)ws_size;
    const float* xs   = (const float*)d_in[0];
    const float* ap   = (const float*)d_in[1];
    const float* act  = (const float*)d_in[2];
    const float* edge = (const float*)d_in[3];
    const float* avail= (const float*)d_in[4];
    const float* ua0  = (const float*)d_in[5];
    const float* g0   = (const float*)d_in[7];
    const float* W1p  = (const float*)d_in[8];
    const float* W2p  = (const float*)d_in[9];
    const float* Wx1a = (const float*)d_in[10];
    const float* We1a = (const float*)d_in[11];
    const float* Wl1a = (const float*)d_in[12];
    const float* Wx1b = (const float*)d_in[13];
    const float* Wl1b = (const float*)d_in[15];
    const float* Wx2  = (const float*)d_in[16];
    const float* We2  = (const float*)d_in[17];
    const float* Wl2  = (const float*)d_in[18];
    const float* WQ   = (const float*)d_in[19];
    float* out = (float*)d_out;

    char* ws = (char*)d_ws;
    // A' (persistent): 16*1024*3072*2 = 100,663,296 B
    unsigned short* Abuf = (unsigned short*)ws;
    char* r2 = ws + 100663296;
    // P/D (fp16) live only until abuild; aliased with B' buffers after:
    unsigned short* Pbuf = (unsigned short*)r2;                      // 33,521,664
    unsigned short* Dbuf = (unsigned short*)(r2 + 33521664);         // 33,521,664 (ends 67,043,328)
    unsigned short* BT1a = (unsigned short*)r2;                      //  6,291,456
    unsigned short* BT1b = (unsigned short*)(r2 + 6291456);          //  6,291,456
    unsigned short* BT2a = (unsigned short*)(r2 + 12582912);         // 12,582,912
    unsigned short* BT2b = (unsigned short*)(r2 + 25165824);         // 12,582,912 (ends 37,748,736)
    float* partial       = (float*)(r2 + 67108864);                  // 50,331,648 (ends 117,440,512)
    float* uaB           = (float*)(r2 + 117440512);                 //  4,194,304
    float* ubB           = (float*)(r2 + 121634816);                 //  4,194,304
    float* x2B           = (float*)(r2 + 125829120);                 //  8,388,608
    float* xaB           = (float*)(r2 + 134217728);                 //     65,536
    unsigned short* BT1[2] = {BT1a, BT1b};
    unsigned short* BT2[2] = {BT2a, BT2b};

    hipMemsetAsync(d_out, 0, BATCH*sizeof(float), stream);
    xa_k<<<64,256,0,stream>>>(xs, ap, act, xaB);
    presence_k<<<dim3(CITIES,BATCH),128,0,stream>>>(edge, W1p, W2p, avail, Pbuf, Dbuf);
    abuild_k<<<dim3(32,32,BATCH),256,0,stream>>>(Pbuf, Dbuf, Abuf);
    binit_k<<<dim3(12,64,BATCH),256,0,stream>>>(ua0, We1a, BT1[0], 64);
    for(int it=0; it<5; it++){
        gemm2_k<256,64,256><<<dim3(4,BATCH,12),256,0,stream>>>(Abuf, BT1[it&1], partial);
        if(it<4)
            reduce1_k<false><<<dim3(16,BATCH),256,0,stream>>>(partial, Wl1a, Wl1b,
                Wx1a, Wx1b, We1a, xaB, BT1[(it+1)&1], uaB, ubB);
        else
            reduce1_k<true><<<dim3(16,BATCH),256,0,stream>>>(partial, Wl1a, Wl1b,
                Wx1a, Wx1b, We1a, xaB, BT1[(it+1)&1], uaB, ubB);
    }
    x2_k<<<dim3(16,BATCH),256,0,stream>>>(uaB, ubB, Wx2, x2B);
    binit_k<<<dim3(12,128,BATCH),256,0,stream>>>(g0, We2, BT2[0], 128);
    for(int it=0; it<5; it++){
        gemm2_k<128,128,512><<<dim3(8,BATCH,6),256,0,stream>>>(Abuf, BT2[it&1], partial);
        if(it<4)
            reduce2_k<false><<<dim3(16,BATCH),256,0,stream>>>(partial, Wl2, x2B,
                We2, WQ, BT2[(it+1)&1], out);
        else
            reduce2_k<true><<<dim3(16,BATCH),256,0,stream>>>(partial, Wl2, x2B,
                We2, WQ, BT2[(it+1)&1], out);
    }
}